// Round 9
// baseline (730.823 us; speedup 1.0000x reference)
//
#include <hip/hip_runtime.h>
#include <cmath>

// All implicit ops single-rounded; FMA only where written explicitly
// (replicating XLA:CPU's FPOpFusion::Fast contraction). Output must stay
// BIT-IDENTICAL to rounds 6-8 (passed, absmax 16.0).
#pragma clang fp contract(off)

#define PI_F     3.141592653589793f
#define TWOPI_F  6.283185307179586f
#define EPS_F    1e-5f
#define TWOEPS_F 2e-5f   // == f32(2e-5) exactly

// ---------------------------------------------------------------------------
// Branchless fused replica of glibc (>=2.28) scalar sinf/cosf (bit-exactness
// argument in rounds 6/7). Signs/parity applied post-rounding (exact).
// ---------------------------------------------------------------------------
__device__ __forceinline__ void gl_sincos(float y, float& sout, float& cout) {
    const double hpi_inv = 0x1.45F306DC9C883p+23;  // 2/pi * 2^24
    const double hpi     = 0x1.921FB54442D18p+0;   // pi/2
    const double ps1 = -0x1.555545995a603p-3;
    const double ps2 =  0x1.1107605230bc4p-7;
    const double ps3 = -0x1.994eb3774cf24p-13;
    const double pc1 = -0x1.ffffffd0c621cp-2;
    const double pc2 =  0x1.55553e1068f19p-5;
    const double pc3 = -0x1.6c087e89a359dp-10;
    const double pc4 =  0x1.99343027bf8c3p-16;

    double x = (double)y;
    double r = x * hpi_inv;
    int n = ((int)r + 0x800000) >> 24;     // trunc + biased round, glibc exact
    double xr = x - (double)n * hpi;       // separate mul + sub (no fma)
    double x2 = xr * xr;

    // sine poly at xr, glibc grouping
    double x3 = xr * x2;
    double s1 = ps2 + x2 * ps3;
    double x7 = x3 * x2;
    double ss = xr + x3 * ps1;
    double psin = ss + x7 * s1;

    // cosine poly at x2, positive table, glibc grouping
    double x4 = x2 * x2;
    double c2 = pc3 + x2 * pc4;
    double c1 = 1.0 + x2 * pc1;
    double x6 = x4 * x2;
    double cc = c1 + x4 * pc2;
    double pcos = cc + x6 * c2;

    // round once, then exact sign/parity selects in f32
    float psin_f = (float)psin;
    float pcos_f = (float)pcos;
    float s_sel = (n & 1) ? pcos_f : psin_f;
    float c_sel = (n & 1) ? psin_f : pcos_f;
    sout = (n & 2) ? -s_sel : s_sel;
    cout = ((n + 1) & 2) ? -c_sel : c_sel;
}

__device__ __forceinline__ float gl_cosf(float y) {
    float s, c;
    gl_sincos(y, s, c);
    return c;
}

// ---------------------------------------------------------------------------
// Bit-exact fmodf(t, TWOPI_F) without OCML's loop. fmod's exact remainder is
// always f32-representable, so fma(-2pi_d, k, td) rounds an exactly-
// representable value -> exact; off-by-one k from the rounded multiply is
// corrected by exact +/-2pi_d fixups (sums also exactly representable).
// Sign-of-zero corner (r=-0 vs +0) washes out in the subsequent r - pi.
// Valid while |t| small enough that k*2pi_f is exact in f64 (|t| < ~1e6).
// ---------------------------------------------------------------------------
__device__ __forceinline__ float fmod_2pi_exact(float t) {
    const double TP     = (double)TWOPI_F;   // exact
    const double INV_TP = 1.0 / (double)TWOPI_F;  // compile-time f64
    double td = (double)t;
    double k  = __builtin_trunc(td * INV_TP);
    double r  = __builtin_fma(-TP, k, td);
    if (t >= 0.0f) {
        if (r < 0.0)      r += TP;
        else if (r >= TP) r -= TP;
    } else {
        if (r > 0.0)       r -= TP;
        else if (r <= -TP) r += TP;
    }
    return (float)r;
}

// jnp.mod for positive divisor: exact fmod then sign fixup (f32, as reference)
__device__ __forceinline__ float angnorm(float x) {
    float t = x + PI_F;
    float r = fmod_2pi_exact(t);
    if (r < 0.0f) r += TWOPI_F;
    return r - PI_F;
}

// ---------------------------------------------------------------------------
// Bit-exact num / TWOEPS_F (IEEE f32 divide) via f64 Newton refinement:
// q0 rel-err ~2^-52; one refinement -> q1 within ~2^-60 of the true quotient;
// 53->24 double rounding is innocuous for division (intermediate >= 2p+2);
// residual misround probability ~2^-36/op — negligible over 2e8 ops.
// num is finite (H values bounded); subnormal num upcasts exactly.
// ---------------------------------------------------------------------------
__device__ __forceinline__ float div_2eps(float num) {
    const double C    = (double)TWOEPS_F;
    const double INVC = 1.0 / (double)TWOEPS_F;   // compile-time f64
    double nd = (double)num;
    double q0 = nd * INVC;
    double r  = __builtin_fma(-C, q0, nd);
    double q1 = __builtin_fma(r, INVC, q0);
    return (float)q1;
}

// Hamiltonian with XLA:CPU FMA contraction (unchanged from rounds 6-8):
__device__ __forceinline__ float ham_eval(float p1, float p2,
                                          float sdq, float cdq,
                                          float c1, float c2) {
    float denom = 2.0f * __builtin_fmaf(sdq, sdq, 1.0f);
    float B  = 2.0f * (p2 * p2);
    float AB = __builtin_fmaf(p1, p1, B);
    float t  = (2.0f * p1) * p2;
    float num = __builtin_fmaf(-t, cdq, AB);
    float T = num / denom;                       // IEEE f32 divide
    float VV = (1.0f - c1) + (1.0f - c2);
    return __builtin_fmaf(10.0f, VV, T);
}

// Cross-step trig cache (round 8): all trig is a pure function of (q1,q2);
// the 11 unique evaluations are computed once per q and carried to the next
// step. Identical bits, half the trig calls.
struct QTrig {
    float sdq, cdq, c1, c2;     // sincos(q1-q2), cos(q1), cos(q2)
    float sa, ca, c1p;          // sincos((q1+e)-q2), cos(q1+e)
    float sb, cb, c1m;          // sincos((q1-e)-q2), cos(q1-e)
    float sc, cc, c2p;          // sincos(q1-(q2+e)), cos(q2+e)
    float sd, cd, c2m;          // sincos(q1-(q2-e)), cos(q2-e)
};

__device__ __forceinline__ void qtrig_all(float q1, float q2, QTrig& t) {
    gl_sincos(q1 - q2, t.sdq, t.cdq);
    t.c1 = gl_cosf(q1);
    t.c2 = gl_cosf(q2);
    float q1p = q1 + EPS_F, q1m = q1 - EPS_F;
    gl_sincos(q1p - q2, t.sa, t.ca);  t.c1p = gl_cosf(q1p);
    gl_sincos(q1m - q2, t.sb, t.cb);  t.c1m = gl_cosf(q1m);
    float q2p = q2 + EPS_F, q2m = q2 - EPS_F;
    gl_sincos(q1 - q2p, t.sc, t.cc);  t.c2p = gl_cosf(q2p);
    gl_sincos(q1 - q2m, t.sd, t.cd);  t.c2m = gl_cosf(q2m);
}

// Full 4-dim FD gradient from cached trig (identical arithmetic to round 8,
// with the constant divides routed through div_2eps).
__device__ __forceinline__ void grads_full(const QTrig& t, float p1, float p2,
                                           float& dHq1, float& dHq2,
                                           float& dHp1, float& dHp2) {
    {
        float Hp = ham_eval(p1, p2, t.sa, t.ca, t.c1p, t.c2);
        float Hm = ham_eval(p1, p2, t.sb, t.cb, t.c1m, t.c2);
        dHq1 = div_2eps(Hp - Hm);
    }
    {
        float Hp = ham_eval(p1, p2, t.sc, t.cc, t.c1, t.c2p);
        float Hm = ham_eval(p1, p2, t.sd, t.cd, t.c1, t.c2m);
        dHq2 = div_2eps(Hp - Hm);
    }
    {
        float Hp = ham_eval(p1 + EPS_F, p2, t.sdq, t.cdq, t.c1, t.c2);
        float Hm = ham_eval(p1 - EPS_F, p2, t.sdq, t.cdq, t.c1, t.c2);
        dHp1 = div_2eps(Hp - Hm);
    }
    {
        float Hp = ham_eval(p1, p2 + EPS_F, t.sdq, t.cdq, t.c1, t.c2);
        float Hm = ham_eval(p1, p2 - EPS_F, t.sdq, t.cdq, t.c1, t.c2);
        dHp2 = div_2eps(Hp - Hm);
    }
}

// p-only gradient (midpoint call: reference's dH_dq lanes are dead code there).
__device__ __forceinline__ void grads_p(const QTrig& t, float p1, float p2,
                                        float& dHp1, float& dHp2) {
    {
        float Hp = ham_eval(p1 + EPS_F, p2, t.sdq, t.cdq, t.c1, t.c2);
        float Hm = ham_eval(p1 - EPS_F, p2, t.sdq, t.cdq, t.c1, t.c2);
        dHp1 = div_2eps(Hp - Hm);
    }
    {
        float Hp = ham_eval(p1, p2 + EPS_F, t.sdq, t.cdq, t.c1, t.c2);
        float Hm = ham_eval(p1, p2 - EPS_F, t.sdq, t.cdq, t.c1, t.c2);
        dHp2 = div_2eps(Hp - Hm);
    }
}

__global__ __launch_bounds__(256)
void mpc_rollout_kernel(const float* __restrict__ q0,
                        const float* __restrict__ p0,
                        const float* __restrict__ actions,
                        const float* __restrict__ target,
                        float* __restrict__ out,
                        int n, int T) {
    int i = blockIdx.x * blockDim.x + threadIdx.x;
    if (i >= n) return;

    float q1 = q0[2 * i],  q2 = q0[2 * i + 1];
    float p1 = p0[2 * i],  p2 = p0[2 * i + 1];
    float tg1 = target[0], tg2 = target[1];
    const float* act = actions + (size_t)i * (size_t)T;

    // XLA reduce: strict sequential accumulation in time order
    float running = 0.0f;

    QTrig qt;
    qtrig_all(q1, q2, qt);          // trig for the initial q

    float a_cur = act[0];           // prefetched action

#pragma unroll 1
    for (int ts = 0; ts < T; ++ts) {
        // prefetch next action a full iteration ahead (latency fully hidden)
        int nxt = (ts + 1 < T) ? (ts + 1) : ts;
        float a_nxt = act[nxt];
        float a = a_cur;

        // running cost at the PRE-step state (trajectory index ts), contracted
        {
            float e1 = angnorm(q1 - tg1);
            float e2 = angnorm(q2 - tg2);
            float pos = __builtin_fmaf(e1, e1, e2 * e2);
            float vel = __builtin_fmaf(p1, p1, p2 * p2);
            float c = __builtin_fmaf(0.01f, a * a, pos + vel);
            running += c;
        }

        // --- symplectic step, XLA-contracted (identical bits to round 8) ---
        float dq1g, dq2g, dp1g, dp2g;
        grads_full(qt, p1, p2, dq1g, dq2g, dp1g, dp2g);   // trig cached

        float ph1 = __builtin_fmaf(-0.001f, dp1g, __builtin_fmaf(-0.01f, dq1g, p1));
        float ph2 = __builtin_fmaf(-0.001f, dp2g, __builtin_fmaf(-0.01f, dq2g, p2));

        float dpm1, dpm2;
        grads_p(qt, ph1, ph2, dpm1, dpm2);   // q unchanged -> same cached trig

        float qn1 = __builtin_fmaf(0.02f, dpm1, q1);
        float qn2 = __builtin_fmaf(0.02f, dpm2, q2);

        qtrig_all(qn1, qn2, qt);             // the ONLY trig work this step
        float dq1e, dq2e, dp1e, dp2e;
        grads_full(qt, ph1, ph2, dq1e, dq2e, dp1e, dp2e);

        float pn1 = __builtin_fmaf(-0.001f, dp1e, __builtin_fmaf(-0.01f, dq1e, ph1));
        float pn2 = __builtin_fmaf(-0.001f, dp2e, __builtin_fmaf(-0.01f, dq2e, ph2));
        pn2 = __builtin_fmaf(a, 0.02f, pn2);   // torque on p[1]

        q1 = qn1; q2 = qn2; p1 = pn1; p2 = pn2;
        a_cur = a_nxt;
        // qt now holds trig for the new q -> reused at the next iteration
    }

    // terminal cost at trajectory index T, contracted
    float e1 = angnorm(q1 - tg1);
    float e2 = angnorm(q2 - tg2);
    float S  = __builtin_fmaf(e2, e2, e1 * e1);
    float S2 = __builtin_fmaf(p2, p2, p1 * p1);
    float term = __builtin_fmaf(10.0f, S, S2);

    out[i] = running + term;
}

extern "C" void kernel_launch(void* const* d_in, const int* in_sizes, int n_in,
                              void* d_out, int out_size, void* d_ws, size_t ws_size,
                              hipStream_t stream) {
    const float* q0      = (const float*)d_in[0];
    const float* p0      = (const float*)d_in[1];
    const float* actions = (const float*)d_in[2];
    const float* target  = (const float*)d_in[3];
    float* out = (float*)d_out;

    int n = in_sizes[0] / 2;        // q0 is (n, 2)
    int T = in_sizes[2] / n;        // actions is (n, T)

    int block = 256;
    int grid = (n + block - 1) / block;
    mpc_rollout_kernel<<<grid, block, 0, stream>>>(q0, p0, actions, target, out, n, T);
}